// Round 2
// baseline (3048.284 us; speedup 1.0000x reference)
//
#include <hip/hip_runtime.h>
#include <hip/hip_bf16.h>

typedef float f32x4 __attribute__((ext_vector_type(4)));
typedef __bf16 bf16x8 __attribute__((ext_vector_type(8)));

__device__ inline unsigned short f2bf_bits(float f) {
    unsigned int u = __builtin_bit_cast(unsigned int, f);
    u += 0x7fffu + ((u >> 16) & 1u);
    return (unsigned short)(u >> 16);
}
__device__ inline float bf_to_f32(unsigned short b) {
    return __builtin_bit_cast(float, (unsigned int)b << 16);
}
__device__ inline float sigf(float x) { return 1.0f / (1.0f + expf(-x)); }

// ---------- split fp32 -> hi/lo bf16 ----------
__global__ __launch_bounds__(256) void split_f32(
        const float* __restrict__ src, unsigned short* __restrict__ hi,
        unsigned short* __restrict__ lo, int n4) {
    int i = blockIdx.x * 256 + threadIdx.x;
    if (i >= n4) return;
    float4 v = reinterpret_cast<const float4*>(src)[i];
    ushort4 h, l;
    h.x = f2bf_bits(v.x); l.x = f2bf_bits(v.x - bf_to_f32(h.x));
    h.y = f2bf_bits(v.y); l.y = f2bf_bits(v.y - bf_to_f32(h.y));
    h.z = f2bf_bits(v.z); l.z = f2bf_bits(v.z - bf_to_f32(h.z));
    h.w = f2bf_bits(v.w); l.w = f2bf_bits(v.w - bf_to_f32(h.w));
    reinterpret_cast<ushort4*>(hi)[i] = h;
    reinterpret_cast<ushort4*>(lo)[i] = l;
}

// ---------- transpose fp32[K][Nn] -> hi/lo bf16[Nn][K] ----------
__global__ __launch_bounds__(256) void transpose_split(
        const float* __restrict__ src, unsigned short* __restrict__ hi,
        unsigned short* __restrict__ lo, int K, int Nn) {
    __shared__ float tile[32][33];
    int n = blockIdx.x * 32 + threadIdx.x;
    int k0 = blockIdx.y * 32;
#pragma unroll
    for (int i = 0; i < 4; i++)
        tile[threadIdx.y + 8 * i][threadIdx.x] = src[(long)(k0 + threadIdx.y + 8 * i) * Nn + n];
    __syncthreads();
    int k = k0 + threadIdx.x;
    int n0 = blockIdx.x * 32;
#pragma unroll
    for (int i = 0; i < 4; i++) {
        float v = tile[threadIdx.x][threadIdx.y + 8 * i];
        unsigned short hb = f2bf_bits(v);
        unsigned short lb = f2bf_bits(v - bf_to_f32(hb));
        long o = (long)(n0 + threadIdx.y + 8 * i) * K + k;
        hi[o] = hb;
        lo[o] = lb;
    }
}

__global__ __launch_bounds__(256) void zero_f32(float* __restrict__ p, int n) {
    int i = blockIdx.x * 256 + threadIdx.x;
    if (i < n) p[i] = 0.0f;
}

// ---------- split-precision MFMA GEMM, C = A*B^T, 3 MFMAs per product ----------
// EPI 0: fp32 out (+bias).  EPI 1: exact-gelu -> hi/lo bf16 out (+bias).
// EPI 2: fused gated-cell: B cols remapped so ni-fragment == gate group; emits
//        c[row][d] and atomically accumulates Sc, Sc2, Scv per row.
template <int EPI>
__global__ __launch_bounds__(256) void gemm_split(
        const unsigned short* __restrict__ Ah, const unsigned short* __restrict__ Al,
        const unsigned short* __restrict__ Bh, const unsigned short* __restrict__ Bl,
        const float* __restrict__ bias,
        int M, int K, int rowStride, int rowDiv,
        float* __restrict__ outf, int ldc,
        unsigned short* __restrict__ outHi, unsigned short* __restrict__ outLo,
        const float* __restrict__ h, float* __restrict__ cOut,
        float* __restrict__ Sc, float* __restrict__ Sc2, float* __restrict__ Scv,
        const float* __restrict__ wdec, const float* __restrict__ g2) {
    __shared__ unsigned short ldsAh[128][72], ldsAl[128][72];
    __shared__ unsigned short ldsBh[128][72], ldsBl[128][72];
    __shared__ float redA[128], redB[128], redC[128];

    const int t = threadIdx.x;
    const int lane = t & 63, w = t >> 6;
    const int wr = w >> 1, wc = w & 1;
    const int l15 = lane & 15, l16 = lane >> 4;
    const int bm = blockIdx.y * 128;
    const int bn = blockIdx.x * 128;
    const int d0 = blockIdx.x * 32;   // EPI2

    f32x4 acc[4][4];
#pragma unroll
    for (int mi = 0; mi < 4; mi++)
#pragma unroll
        for (int ni = 0; ni < 4; ni++)
            acc[mi][ni] = {0.f, 0.f, 0.f, 0.f};

    for (int kt = 0; kt < K; kt += 64) {
        __syncthreads();
#pragma unroll
        for (int i = 0; i < 4; i++) {
            int cidx = i * 256 + t;
            int sr = cidx >> 3, ck = (cidx & 7) * 8;
            int m = bm + sr;
            if (m > M - 1) m = M - 1;
            long aoff = (long)(m + m / rowDiv) * rowStride + kt + ck;
            *reinterpret_cast<float4*>(&ldsAh[sr][ck]) = *reinterpret_cast<const float4*>(Ah + aoff);
            *reinterpret_cast<float4*>(&ldsAl[sr][ck]) = *reinterpret_cast<const float4*>(Al + aoff);
            int bcol = (EPI == 2) ? (((sr >> 4) & 3) * 1024 + d0 + ((sr >> 6) << 4) + (sr & 15))
                                  : (bn + sr);
            long boff = (long)bcol * K + kt + ck;
            *reinterpret_cast<float4*>(&ldsBh[sr][ck]) = *reinterpret_cast<const float4*>(Bh + boff);
            *reinterpret_cast<float4*>(&ldsBl[sr][ck]) = *reinterpret_cast<const float4*>(Bl + boff);
        }
        __syncthreads();
#pragma unroll
        for (int half = 0; half < 2; half++) {
            const int ko = half * 32 + l16 * 8;
            bf16x8 fah[4], fal[4], fbh[4], fbl[4];
#pragma unroll
            for (int mi = 0; mi < 4; mi++) {
                fah[mi] = *reinterpret_cast<const bf16x8*>(&ldsAh[wr * 64 + mi * 16 + l15][ko]);
                fal[mi] = *reinterpret_cast<const bf16x8*>(&ldsAl[wr * 64 + mi * 16 + l15][ko]);
            }
#pragma unroll
            for (int ni = 0; ni < 4; ni++) {
                fbh[ni] = *reinterpret_cast<const bf16x8*>(&ldsBh[wc * 64 + ni * 16 + l15][ko]);
                fbl[ni] = *reinterpret_cast<const bf16x8*>(&ldsBl[wc * 64 + ni * 16 + l15][ko]);
            }
#pragma unroll
            for (int mi = 0; mi < 4; mi++)
#pragma unroll
                for (int ni = 0; ni < 4; ni++) {
                    acc[mi][ni] = __builtin_amdgcn_mfma_f32_16x16x32_bf16(fah[mi], fbh[ni], acc[mi][ni], 0, 0, 0);
                    acc[mi][ni] = __builtin_amdgcn_mfma_f32_16x16x32_bf16(fah[mi], fbl[ni], acc[mi][ni], 0, 0, 0);
                    acc[mi][ni] = __builtin_amdgcn_mfma_f32_16x16x32_bf16(fal[mi], fbh[ni], acc[mi][ni], 0, 0, 0);
                }
        }
    }

    if (EPI == 0 || EPI == 1) {
#pragma unroll
        for (int ni = 0; ni < 4; ni++) {
            const int col = bn + wc * 64 + ni * 16 + l15;
            const float bv = bias[col];
#pragma unroll
            for (int mi = 0; mi < 4; mi++)
#pragma unroll
                for (int v = 0; v < 4; v++) {
                    const int row = bm + wr * 64 + mi * 16 + l16 * 4 + v;
                    if (row < M) {
                        float val = acc[mi][ni][v] + bv;
                        if (EPI == 1) {
                            val = 0.5f * val * (1.0f + erff(val * 0.70710678118654752440f));
                            unsigned short hb = f2bf_bits(val);
                            unsigned short lb = f2bf_bits(val - bf_to_f32(hb));
                            outHi[(long)row * ldc + col] = hb;
                            outLo[(long)row * ldc + col] = lb;
                        } else {
                            outf[(long)row * ldc + col] = val;
                        }
                    }
                }
        }
    } else {
        // fused cell epilogue: thread owns d = d0 + wc*16 + l15; ni == gate group
        const int d = d0 + wc * 16 + l15;
        const float bg0 = bias[d], bg1 = bias[1024 + d];
        const float bg2 = bias[2048 + d], bg3 = bias[3072 + d];
        const float gw = g2[d] * wdec[d];
        __syncthreads();
        if (t < 128) { redA[t] = 0.f; redB[t] = 0.f; redC[t] = 0.f; }
        __syncthreads();
#pragma unroll
        for (int mi = 0; mi < 4; mi++) {
#pragma unroll
            for (int v = 0; v < 4; v++) {
                const int rl = wr * 64 + mi * 16 + l16 * 4 + v;
                const int row = bm + rl;
                const bool ok = row < M;
                float s1 = 0.f, s2 = 0.f, s3 = 0.f;
                if (ok) {
                    float t0 = acc[mi][0][v] + bg0;
                    float t1 = acc[mi][1][v] + bg1;
                    float t2 = acc[mi][2][v] + bg2;
                    float t3 = acc[mi][3][v] + bg3;
                    long q = row + row / 511;
                    float lv = h[q * 1024 + d];
                    float rv = h[q * 1024 + 1024 + d];
                    float cv = sigf(t0) * lv + sigf(t1) * rv + sigf(t2) * t3;
                    cOut[(long)row * 1024 + d] = cv;
                    s1 = cv; s2 = cv * cv; s3 = cv * gw;
                }
#pragma unroll
                for (int off = 1; off < 16; off <<= 1) {
                    s1 += __shfl_xor(s1, off);
                    s2 += __shfl_xor(s2, off);
                    s3 += __shfl_xor(s3, off);
                }
                if (ok && l15 == 0) {
                    atomicAdd(&redA[rl], s1);
                    atomicAdd(&redB[rl], s2);
                    atomicAdd(&redC[rl], s3);
                }
            }
        }
        __syncthreads();
        if (t < 128) {
            int row = bm + t;
            if (row < M) {
                atomicAdd(&Sc[row], redA[t]);
                atomicAdd(&Sc2[row], redB[t]);
                atomicAdd(&Scv[row], redC[t]);
            }
        }
    }
}

// ---------- LayerNorm over D=1024: fp32 out + hi/lo bf16 out ----------
__device__ inline float block_sum4(float v, float* sm) {
    const int lane = threadIdx.x & 63, w = threadIdx.x >> 6;
#pragma unroll
    for (int off = 1; off < 64; off <<= 1) v += __shfl_xor(v, off);
    if (lane == 0) sm[w] = v;
    __syncthreads();
    float r = sm[0] + sm[1] + sm[2] + sm[3];
    __syncthreads();
    return r;
}

__global__ __launch_bounds__(256) void ln_kernel(
        const float* __restrict__ in, const float* __restrict__ g, const float* __restrict__ b,
        float* __restrict__ out_f32, unsigned short* __restrict__ out_hi,
        unsigned short* __restrict__ out_lo) {
    __shared__ float sm[4];
    const long r = blockIdx.x;
    const int d0 = threadIdx.x * 4;
    float4 v = *reinterpret_cast<const float4*>(in + r * 1024 + d0);
    float mu = block_sum4(v.x + v.y + v.z + v.w, sm) * (1.0f / 1024.0f);
    float dx = v.x - mu, dy = v.y - mu, dz = v.z - mu, dw = v.w - mu;
    float var = block_sum4(dx * dx + dy * dy + dz * dz + dw * dw, sm) * (1.0f / 1024.0f);
    float rstd = rsqrtf(var + 1e-5f);
    float4 gv = *reinterpret_cast<const float4*>(g + d0);
    float4 bv = *reinterpret_cast<const float4*>(b + d0);
    float4 o;
    o.x = dx * rstd * gv.x + bv.x;
    o.y = dy * rstd * gv.y + bv.y;
    o.z = dz * rstd * gv.z + bv.z;
    o.w = dw * rstd * gv.w + bv.w;
    *reinterpret_cast<float4*>(out_f32 + r * 1024 + d0) = o;
    ushort4 hb, lb;
    hb.x = f2bf_bits(o.x); lb.x = f2bf_bits(o.x - bf_to_f32(hb.x));
    hb.y = f2bf_bits(o.y); lb.y = f2bf_bits(o.y - bf_to_f32(hb.y));
    hb.z = f2bf_bits(o.z); lb.z = f2bf_bits(o.z - bf_to_f32(hb.z));
    hb.w = f2bf_bits(o.w); lb.w = f2bf_bits(o.w - bf_to_f32(hb.w));
    *reinterpret_cast<ushort4*>(out_hi + r * 1024 + d0) = hb;
    *reinterpret_cast<ushort4*>(out_lo + r * 1024 + d0) = lb;
}

// ---------- comp + top-5 (stable ties: lower index wins) ----------
__global__ __launch_bounds__(512) void topk_kernel(
        const float* __restrict__ Sc, const float* __restrict__ Sc2, const float* __restrict__ Scv,
        const float* __restrict__ g2, const float* __restrict__ b2ln,
        const float* __restrict__ wdec, const float* __restrict__ bdec,
        int* __restrict__ idx) {
    __shared__ float vals[512];
    __shared__ float vf[512];
    __shared__ int vi[512];
    __shared__ float red[512];
    const int n = blockIdx.x, t = threadIdx.x;
    float pg = g2[t] * wdec[t] + g2[t + 512] * wdec[t + 512];
    float pb = b2ln[t] * wdec[t] + b2ln[t + 512] * wdec[t + 512];
    red[t] = pg; __syncthreads();
    for (int s2 = 256; s2 > 0; s2 >>= 1) { if (t < s2) red[t] += red[t + s2]; __syncthreads(); }
    float sgw = red[0]; __syncthreads();
    red[t] = pb; __syncthreads();
    for (int s2 = 256; s2 > 0; s2 >>= 1) { if (t < s2) red[t] += red[t + s2]; __syncthreads(); }
    float sbw = red[0]; __syncthreads();

    float cmp = -3.0e38f;
    if (t < 511) {
        long m = (long)n * 511 + t;
        float mu = Sc[m] * (1.0f / 1024.0f);
        float var = Sc2[m] * (1.0f / 1024.0f) - mu * mu;
        float rstd = rsqrtf(var + 1e-5f);
        cmp = (Scv[m] - mu * sgw) * rstd + sbw + bdec[0];
    }
    vals[t] = cmp;
    __syncthreads();
    for (int r = 0; r < 5; r++) {
        vf[t] = vals[t];
        vi[t] = t;
        __syncthreads();
        for (int strd = 256; strd > 0; strd >>= 1) {
            if (t < strd) {
                float ov = vf[t + strd];
                int oi = vi[t + strd];
                if (ov > vf[t] || (ov == vf[t] && oi < vi[t])) { vf[t] = ov; vi[t] = oi; }
            }
            __syncthreads();
        }
        if (t == 0) {
            idx[n * 5 + r] = vi[0];
            vals[vi[0]] = -3.0e38f;
        }
        __syncthreads();
    }
}

// ---------- final gather (new_h reconstructed on the fly) ----------
__global__ __launch_bounds__(256) void gather_kernel(
        const float* __restrict__ h, const float* __restrict__ c,
        const float* __restrict__ Sc, const float* __restrict__ Sc2,
        const float* __restrict__ g2, const float* __restrict__ b2ln,
        const int* __restrict__ idx, float* __restrict__ out) {
    const long b = blockIdx.x;
    const int n = (int)(b / 2555);
    const int rem = (int)(b % 2555);
    const int k = rem / 511;
    const int s = rem % 511;
    const int tsel = idx[n * 5 + k];
    const int d0 = threadIdx.x * 4;
    float4 o;
    if (s == tsel) {
        long m = (long)n * 511 + s;
        float mu = Sc[m] * (1.0f / 1024.0f);
        float var = Sc2[m] * (1.0f / 1024.0f) - mu * mu;
        float rstd = rsqrtf(var + 1e-5f);
        float4 cv = *reinterpret_cast<const float4*>(c + m * 1024 + d0);
        float4 gv = *reinterpret_cast<const float4*>(g2 + d0);
        float4 bv = *reinterpret_cast<const float4*>(b2ln + d0);
        o.x = (cv.x - mu) * rstd * gv.x + bv.x;
        o.y = (cv.y - mu) * rstd * gv.y + bv.y;
        o.z = (cv.z - mu) * rstd * gv.z + bv.z;
        o.w = (cv.w - mu) * rstd * gv.w + bv.w;
    } else {
        long q = (long)n * 512 + s + (s > tsel ? 1 : 0);
        o = *reinterpret_cast<const float4*>(h + q * 1024 + d0);
    }
    *reinterpret_cast<float4*>(out + b * 1024 + d0) = o;
}

// ---------- launch ----------
extern "C" void kernel_launch(void* const* d_in, const int* in_sizes, int n_in,
                              void* d_out, int out_size, void* d_ws, size_t ws_size,
                              hipStream_t stream) {
    const float* x      = (const float*)d_in[0];
    const float* w_word = (const float*)d_in[1];
    const float* b_word = (const float*)d_in[2];
    const float* ln_g   = (const float*)d_in[3];
    const float* ln_b   = (const float*)d_in[4];
    const float* w1     = (const float*)d_in[5];
    const float* b1     = (const float*)d_in[6];
    const float* w2     = (const float*)d_in[7];
    const float* b2     = (const float*)d_in[8];
    const float* ln2_g  = (const float*)d_in[9];
    const float* ln2_b  = (const float*)d_in[10];
    const float* w_dec  = (const float*)d_in[11];
    const float* b_dec  = (const float*)d_in[12];

    char* ws = (char*)d_ws;
    float*          h_pre  = (float*)(ws + 0);                  // 32 MiB, then c
    float*          c      = (float*)(ws + 0);
    float*          h      = (float*)(ws + 33554432);           // 32 MiB
    unsigned short* h_hi   = (unsigned short*)(ws + 67108864);  // 16 MiB
    unsigned short* h_lo   = (unsigned short*)(ws + 83886080);  // 16 MiB
    unsigned short* x_hi   = (unsigned short*)(ws + 100663296); // 16 MiB
    unsigned short* x_lo   = (unsigned short*)(ws + 117440512); // 16 MiB
    unsigned short* w1T_hi = (unsigned short*)(ws + 134217728); // 16 MiB
    unsigned short* w1T_lo = (unsigned short*)(ws + 150994944); // 16 MiB
    unsigned short* wwT_hi = (unsigned short*)(ws + 167772160); // 2 MiB
    unsigned short* wwT_lo = (unsigned short*)(ws + 169869312); // 2 MiB
    unsigned short* w2T_hi = (unsigned short*)(ws + 67108864);  // reuses h_hi/h_lo after GEMM2
    unsigned short* w2T_lo = (unsigned short*)(ws + 100663296); // reuses x_hi/x_lo after GEMM1
    float*          Sc     = (float*)(ws + 171966464);
    float*          Sc2    = (float*)(ws + 171999232);
    float*          Scv    = (float*)(ws + 172031   * 1000 + 0); // placeholder replaced below
    Scv = (float*)(ws + 172032000);
    int*            idx    = (int*)(ws + 172064768);

    unsigned short* inter_hi = (unsigned short*)d_out;
    unsigned short* inter_lo = (unsigned short*)((char*)d_out + 66977792);

    // split x; transpose+split w_word, w1
    split_f32<<<8192, 256, 0, stream>>>(x, x_hi, x_lo, 2097152);
    transpose_split<<<dim3(32, 32), dim3(32, 8), 0, stream>>>(w_word, wwT_hi, wwT_lo, 1024, 1024);
    transpose_split<<<dim3(128, 64), dim3(32, 8), 0, stream>>>(w1, w1T_hi, w1T_lo, 2048, 4096);

    // GEMM1: h_pre = x @ w_word + b_word   (fp32 out)
    gemm_split<0><<<dim3(8, 64), 256, 0, stream>>>(
            x_hi, x_lo, wwT_hi, wwT_lo, b_word,
            8192, 1024, 1024, 1 << 30,
            h_pre, 1024, nullptr, nullptr,
            nullptr, nullptr, nullptr, nullptr, nullptr, nullptr, nullptr);
    // h = LN(h_pre)  (fp32 + hi/lo bf16)
    ln_kernel<<<8192, 256, 0, stream>>>(h_pre, ln_g, ln_b, h, h_hi, h_lo);
    // GEMM2: inter = gelu(concat(l,r) @ w1 + b1)  -> hi/lo bf16 in d_out
    gemm_split<1><<<dim3(32, 64), 256, 0, stream>>>(
            h_hi, h_lo, w1T_hi, w1T_lo, b1,
            8176, 2048, 1024, 511,
            nullptr, 4096, inter_hi, inter_lo,
            nullptr, nullptr, nullptr, nullptr, nullptr, nullptr, nullptr);
    // transpose+split w2 (into regions freed by h_hi/lo and x_hi/lo)
    transpose_split<<<dim3(128, 128), dim3(32, 8), 0, stream>>>(w2, w2T_hi, w2T_lo, 4096, 4096);
    // zero S accumulators (Sc, Sc2 contiguous; Scv separate)
    zero_f32<<<64, 256, 0, stream>>>(Sc, 16384);
    zero_f32<<<64, 256, 0, stream>>>(Sc2, 16384);
    zero_f32<<<64, 256, 0, stream>>>(Scv, 16384);
    // GEMM3 fused cell: c + S accumulators
    gemm_split<2><<<dim3(32, 64), 256, 0, stream>>>(
            inter_hi, inter_lo, w2T_hi, w2T_lo, b2,
            8176, 4096, 4096, 1 << 30,
            nullptr, 0, nullptr, nullptr,
            h, c, Sc, Sc2, Scv, w_dec, ln2_g);
    // comp + top-5
    topk_kernel<<<16, 512, 0, stream>>>(Sc, Sc2, Scv, ln2_g, ln2_b, w_dec, b_dec, idx);
    // final gather
    gather_kernel<<<40880, 256, 0, stream>>>(h, c, Sc, Sc2, ln2_g, ln2_b, idx, (float*)d_out);
}